// Round 10
// baseline (169.868 us; speedup 1.0000x reference)
//
#include <hip/hip_runtime.h>
#include <stdint.h>

#define N_BASES 5
#define WELEM (128 * 128 * 3 * 3) /* 147456 per base */

typedef __attribute__((ext_vector_type(4))) float f32x4;
typedef __attribute__((ext_vector_type(8))) short bf16x8;

__device__ __forceinline__ unsigned short f2bf(float v) {
  union { float f; uint32_t u; } un;
  un.f = v;
  uint32_t r = un.u + 0x7FFFu + ((un.u >> 16) & 1u);
  return (unsigned short)(r >> 16);
}

// ---- kernel 1: per-(base,chunk) |w| partial sums (320 blocks).
// The NCHW->NHWC transpose that used to live here is now FUSED into
// conv_kernel's patch staging (R10): the 55 MB xpad intermediate and its
// read-back are deleted from the pipeline.
__global__ __launch_bounds__(256) void wsum_kernel(
    const float* __restrict__ w, float* __restrict__ csum_part) {
  int id = blockIdx.x;
  int n = id >> 6;
  int chunk = id & 63;
  const f32x4* wb = (const f32x4*)(w + (size_t)n * WELEM + chunk * 2304);
  float s = 0.f;
  for (int i = threadIdx.x; i < 576; i += 256) {
    f32x4 v = wb[i];
    s += fabsf(v.x) + fabsf(v.y) + fabsf(v.z) + fabsf(v.w);
  }
  #pragma unroll
  for (int off = 32; off > 0; off >>= 1) s += __shfl_down(s, off);
  __shared__ float red[4];
  if ((threadIdx.x & 63) == 0) red[threadIdx.x >> 6] = s;
  __syncthreads();
  if (threadIdx.x == 0) csum_part[id] = red[0] + red[1] + red[2] + red[3];
}

// ---- kernel 2: W_eff -> bf16, laid out for DIRECT per-wave global reads.
// Element (o, i, t) with i = kb*32 + quad*8 + e:
// wq[(((t*4 + kb)*4 + quad)*128 + o)*8 + e]. ----
__global__ __launch_bounds__(256) void binweight_kernel(
    const float* __restrict__ w, const float* __restrict__ csum_part,
    const float* __restrict__ scales, unsigned short* __restrict__ wq) {
  __shared__ float parts[320];
  __shared__ float coef[N_BASES];
  for (int i = threadIdx.x; i < 320; i += 256) parts[i] = csum_part[i];
  __syncthreads();
  if (threadIdx.x < N_BASES) {
    float s = 0.f;
    #pragma unroll 8
    for (int k = 0; k < 64; ++k) s += parts[threadIdx.x * 64 + k];
    coef[threadIdx.x] = scales[threadIdx.x] * s * (1.0f / (float)WELEM);
  }
  __syncthreads();
  int f = blockIdx.x * 256 + threadIdx.x;  // f = o*1152 + i*9 + t
  float s = 0.f;
  #pragma unroll
  for (int n = 0; n < N_BASES; ++n) {
    float cn = coef[n];
    float v = w[n * WELEM + f];
    s += (v > 0.f) ? cn : ((v < 0.f) ? -cn : 0.f);
  }
  int o = f / 1152;
  int rem = f - o * 1152;
  int i = rem / 9;
  int t = rem - i * 9;
  int kb = i >> 5;          // 32-ch K-slice within the tap
  int quad = (i >> 3) & 3;  // 8-ch granule within the slice
  int e = i & 7;
  wq[((size_t)((t * 4 + kb) * 4 + quad) * 128 + o) * 8 + e] = f2bf(s);
}

// ---- kernel 3: implicit-GEMM conv with FUSED input transpose+pad.
// EXACT R7 compute structure (best: 47.0 us): grid 896, 1 img x 8h x 16w
// block, wave M=64 x N=64, af ring-2 (distance 1) + B ring-4 (distance 2),
// 4-phase unroll-1 body, zero barriers in the K-loop. R9's XCD swizzle
// was NULL -> reverted (b = blk&31).
// NEW: staging reads x DIRECTLY (NCHW fp32): per (sp, c16) chunk, 8
// scalar f32 loads at stride 3136 (channels c16*8..+7), f2bf, one b128
// swizzled LDS write -- identical patch layout, K-loop untouched. Border
// px predicated to 1.0 (reference pads with constant 1.0). x is 51 MB =
// L3-resident; each 64B line is reused ~9x across sp within a block ->
// L2-hit after first touch. This deletes the 55 MB xpad write + its
// read-back + one ~1856-block dispatch from the pipeline.
// Tripwire: conv > 62 us => scalar staging too costly, revert to split.
__global__ __launch_bounds__(256, 3) void conv_kernel(
    const float* __restrict__ x, const unsigned short* __restrict__ wq,
    float* __restrict__ out) {
  __shared__ unsigned short patch[23040];  // 180 sp x 128 ch (46.1 KB)

  const int tid = threadIdx.x;
  const int blk = blockIdx.x;
  const int b = blk & 31;        // image
  const int tile = blk >> 5;     // 0..27 = hi*4 + wi
  const int hi = tile >> 2;      // 0..6
  const int wi = tile & 3;
  const int h0 = hi * 8;
  const int w0 = (wi == 3) ? 40 : wi * 16;

  const int lane = tid & 63;
  const int wave = tid >> 6;
  const int mh = wave >> 1;
  const int nh = wave & 1;
  const int l15 = lane & 15;
  const int quad = lane >> 4;

  // per-lane B base: covers quad + nh + l15; per-step stride 4096 shorts,
  // per-nf stride 128 shorts.
  const unsigned short* wlane =
      wq + ((size_t)quad * 128 + nh * 64 + l15) * 8;

  // ---- prologue: B prefetch for steps 0,1; latency hides under staging ----
  bf16x8 b0[4], b1[4], b2[4], b3[4];
  #pragma unroll
  for (int nf = 0; nf < 4; ++nf)
    b0[nf] = *(const bf16x8*)(wlane + nf * 128);
  #pragma unroll
  for (int nf = 0; nf < 4; ++nf)
    b1[nf] = *(const bf16x8*)(wlane + (size_t)4096 + nf * 128);

  // ---- stage patch from x (fused transpose+pad): 180 sp x 16 chunks ----
  const float* xb = x + (size_t)b * 128 * 3136;
  for (int i = tid; i < 2880; i += 256) {
    int sp = i >> 4;
    int c16 = i & 15;
    int ph = sp / 18;           // 0..9
    int pw = sp - ph * 18;      // 0..17
    int gh = h0 + ph - 1;       // -1..56
    int gw = w0 + pw - 1;       // -1..56
    union { uint4 q; unsigned short h[8]; } u;
    if ((unsigned)gh < 56u && (unsigned)gw < 56u) {
      const float* src = xb + (size_t)(c16 * 8) * 3136 + gh * 56 + gw;
      #pragma unroll
      for (int j = 0; j < 8; ++j) u.h[j] = f2bf(src[(size_t)j * 3136]);
    } else {
      #pragma unroll
      for (int j = 0; j < 8; ++j) u.h[j] = 0x3F80;  // pad = 1.0
    }
    *(uint4*)&patch[sp * 128 + ((c16 ^ (sp & 7)) << 3)] = u.q;
  }
  __syncthreads();  // patch ready -- the ONLY barrier in this kernel

  f32x4 acc[4][4];
  #pragma unroll
  for (int mf = 0; mf < 4; ++mf)
    #pragma unroll
    for (int nf = 0; nf < 4; ++nf) acc[mf][nf] = (f32x4)0.f;

  // step s = t*4 + kb, t = tap (kh,kw), kb = 32-ch K-slice.
  auto pf_af = [&](int s, bf16x8 (&af)[4]) {
    const int sc = (s < 36) ? s : 35;  // clamped dup on final iters, unused
    const int t = sc >> 2;
    const int kb = sc & 3;
    const int kh = (t * 11) >> 5;  // t/3 for t in 0..8
    const int kw = t - 3 * kh;
    #pragma unroll
    for (int mf = 0; mf < 4; ++mf) {
      const int sp = (mh * 4 + mf + kh) * 18 + l15 + kw;
      af[mf] = *(const bf16x8*)&patch[sp * 128 +
                                      (((kb * 4 + quad) ^ (sp & 7)) << 3)];
    }
  };
  auto pf_b = [&](int s, bf16x8 (&br)[4]) {
    const int sc = (s < 36) ? s : 35;  // clamped dup on final iters, unused
    #pragma unroll
    for (int nf = 0; nf < 4; ++nf)
      br[nf] = *(const bf16x8*)(wlane + (size_t)sc * 4096 + nf * 128);
  };
  auto compute = [&](bf16x8 (&af)[4], bf16x8 (&br)[4]) {
    #pragma unroll
    for (int mf = 0; mf < 4; ++mf)
      #pragma unroll
      for (int nf = 0; nf < 4; ++nf)
        acc[mf][nf] = __builtin_amdgcn_mfma_f32_16x16x32_bf16(
            af[mf], br[nf], acc[mf][nf], 0, 0, 0);
  };

  bf16x8 afA[4], afB[4];
  pf_af(0, afA);  // first-use stall once, then pipelined

  #pragma unroll 1
  for (int d = 0; d < 9; ++d) {
    const int s = d * 4;
    pf_af(s + 1, afB); pf_b(s + 2, b2); compute(afA, b0);
    pf_af(s + 2, afA); pf_b(s + 3, b3); compute(afB, b1);
    pf_af(s + 3, afB); pf_b(s + 4, b0); compute(afA, b2);
    pf_af(s + 4, afA); pf_b(s + 5, b1); compute(afB, b3);
  }

  // ---- epilogue: lane's f32x4 = w0+quad*4..+3 at h = h0+mh*4+mf, cout o.
  // Full 64-B sectors per (o,h); normal stores (R6 lesson: NT stores
  // amplify HBM writes). ----
  #pragma unroll
  for (int mf = 0; mf < 4; ++mf) {
    int h = h0 + mh * 4 + mf;
    #pragma unroll
    for (int nf = 0; nf < 4; ++nf) {
      int o = nh * 64 + nf * 16 + l15;
      float* p = out + (((size_t)b * 128 + o) * 56 + h) * 56 + w0 + quad * 4;
      *(f32x4*)p = acc[mf][nf];
    }
  }
}

extern "C" void kernel_launch(void* const* d_in, const int* in_sizes, int n_in,
                              void* d_out, int out_size, void* d_ws, size_t ws_size,
                              hipStream_t stream) {
  const float* x = (const float*)d_in[0];       // [32,128,56,56]
  const float* w = (const float*)d_in[1];       // [5,128,128,3,3]
  const float* scales = (const float*)d_in[2];  // [5]
  float* out = (float*)d_out;                   // [32,128,56,56]

  float* csum_part = (float*)d_ws;                              // 320 floats
  unsigned short* wq = (unsigned short*)((char*)d_ws + 4096);   // 36*4096 bf16

  wsum_kernel<<<320, 256, 0, stream>>>(w, csum_part);
  binweight_kernel<<<576, 256, 0, stream>>>(w, csum_part, scales, wq);
  conv_kernel<<<28 * 32, 256, 0, stream>>>(x, wq, out);
}

// Round 11
// 145.075 us; speedup vs baseline: 1.1709x; 1.1709x over previous
//
#include <hip/hip_runtime.h>
#include <stdint.h>

#define N_BASES 5
#define WELEM (128 * 128 * 3 * 3) /* 147456 per base */

typedef __attribute__((ext_vector_type(4))) float f32x4;
typedef __attribute__((ext_vector_type(8))) short bf16x8;
typedef __attribute__((ext_vector_type(4))) unsigned short u16x4;

__device__ __forceinline__ unsigned short f2bf(float v) {
  union { float f; uint32_t u; } un;
  un.f = v;
  uint32_t r = un.u + 0x7FFFu + ((un.u >> 16) & 1u);
  return (unsigned short)(r >> 16);
}

// ---- kernel 1 (fused): blocks 0..1855 = x NCHW fp32 -> padded NHWC bf16;
//      blocks 1856..2175 = per-(base,chunk) |w| partial sums.
// (R10 lesson: fusing this transpose into conv staging de-coalesces the
// x reads and costs +37 us in conv for a 13.5 us dispatch saving. The
// split transpose is already near its 101 MB BW floor ~ 13.5 us.)
__global__ __launch_bounds__(256) void prep_fused(
    const float* __restrict__ x, const float* __restrict__ w,
    unsigned short* __restrict__ xp, float* __restrict__ csum_part) {
  int bi = blockIdx.x;
  if (bi >= 1856) {
    int id = bi - 1856;
    int n = id >> 6;
    int chunk = id & 63;
    const f32x4* wb = (const f32x4*)(w + (size_t)n * WELEM + chunk * 2304);
    float s = 0.f;
    for (int i = threadIdx.x; i < 576; i += 256) {
      f32x4 v = wb[i];
      s += fabsf(v.x) + fabsf(v.y) + fabsf(v.z) + fabsf(v.w);
    }
    #pragma unroll
    for (int off = 32; off > 0; off >>= 1) s += __shfl_down(s, off);
    __shared__ float red[4];
    if ((threadIdx.x & 63) == 0) red[threadIdx.x >> 6] = s;
    __syncthreads();
    if (threadIdx.x == 0) csum_part[id] = red[0] + red[1] + red[2] + red[3];
    return;
  }
  int tid = threadIdx.x;
  int b = bi / 58;
  int hp = bi - b * 58;
  unsigned short* dst = xp + ((size_t)b * 58 + hp) * 58 * 128;
  int gh = hp - 1;
  uint4 ones = make_uint4(0x3F803F80u, 0x3F803F80u, 0x3F803F80u, 0x3F803F80u);
  if ((unsigned)gh >= 56u) {  // full pad row
    for (int i = tid; i < 928; i += 256) ((uint4*)dst)[i] = ones;
    return;
  }
  // tile[w][cc]: w = 0..55, cc = swizzled 4-short chunk 0..31 (even XOR ->
  // pair adjacency preserved for 16B reads).
  __shared__ unsigned short tile[56 * 128];  // 14 KB
  const float* xb = x + (size_t)b * 128 * 3136 + (size_t)gh * 56;
  #pragma unroll
  for (int k = 0; k < 7; ++k) {
    int g = k * 256 + tid;     // 0..1791
    int c4 = g / 56;           // 0..31
    int ww = g - c4 * 56;      // 0..55
    const float* sp = xb + (size_t)(4 * c4) * 3136 + ww;
    u16x4 pk;
    pk.x = f2bf(sp[0]);
    pk.y = f2bf(sp[3136]);
    pk.z = f2bf(sp[2 * 3136]);
    pk.w = f2bf(sp[3 * 3136]);
    *(u16x4*)&tile[ww * 128 + ((c4 ^ ((ww & 15) << 1)) << 2)] = pk;
  }
  __syncthreads();
  for (int i = tid; i < 928; i += 256) {
    int wp = i >> 4;     // 0..57
    int e = i & 15;      // 16B chunk within the 128-ch row
    uint4 v;
    if (wp == 0 || wp == 57) {
      v = ones;
    } else {
      int r = wp - 1;
      v = *(const uint4*)&tile[r * 128 + (((2 * e) ^ ((r & 15) << 1)) << 2)];
    }
    *(uint4*)(dst + (size_t)wp * 128 + e * 8) = v;
  }
}

// ---- kernel 2: W_eff -> bf16, laid out for DIRECT per-wave global reads.
// Element (o, i, t) with i = kb*32 + quad*8 + e:
// wq[(((t*4 + kb)*4 + quad)*128 + o)*8 + e]. ----
__global__ __launch_bounds__(256) void binweight_kernel(
    const float* __restrict__ w, const float* __restrict__ csum_part,
    const float* __restrict__ scales, unsigned short* __restrict__ wq) {
  __shared__ float parts[320];
  __shared__ float coef[N_BASES];
  for (int i = threadIdx.x; i < 320; i += 256) parts[i] = csum_part[i];
  __syncthreads();
  if (threadIdx.x < N_BASES) {
    float s = 0.f;
    #pragma unroll 8
    for (int k = 0; k < 64; ++k) s += parts[threadIdx.x * 64 + k];
    coef[threadIdx.x] = scales[threadIdx.x] * s * (1.0f / (float)WELEM);
  }
  __syncthreads();
  int f = blockIdx.x * 256 + threadIdx.x;  // f = o*1152 + i*9 + t
  float s = 0.f;
  #pragma unroll
  for (int n = 0; n < N_BASES; ++n) {
    float cn = coef[n];
    float v = w[n * WELEM + f];
    s += (v > 0.f) ? cn : ((v < 0.f) ? -cn : 0.f);
  }
  int o = f / 1152;
  int rem = f - o * 1152;
  int i = rem / 9;
  int t = rem - i * 9;
  int kb = i >> 5;          // 32-ch K-slice within the tap
  int quad = (i >> 3) & 3;  // 8-ch granule within the slice
  int e = i & 7;
  wq[((size_t)((t * 4 + kb) * 4 + quad) * 128 + o) * 8 + e] = f2bf(s);
}

// ---- kernel 3: implicit-GEMM conv, ZERO barriers in the K-loop.
// EXACT R7 configuration -- the session best (total 146.0 us, conv 47.0):
// grid 896, 1 img x 8h x 16w block, wave M=64 x N=64, af ring-2
// (distance 1) + B ring-4 (distance 2), 4-phase unroll-1 body, 80 VGPR,
// no spill. Session ledger for this kernel:
//   - barriers/glds (R0/R1): 56/50.6   - reg-B depth-1/3 (R3/R4): 52.8/54.3
//   - dual-ring (R7): 47.0 BEST        - af ring-3 (R8): spills, 72
//   - XCD swizzle (R9): null           - NT stores (R6): +20 MB HBM, worse
//   - fused transpose (R10): staging de-coalesces, 86
// Structure is at equilibrium: LDS 46 KB + 144 unified regs both pin
// occupancy at 3 blocks/CU; shrinking wave-M to raise TLP doubles per-CU
// L2 B-traffic (B-dup ~ 1/M_wave); no pipe >35% busy. ----
__global__ __launch_bounds__(256, 3) void conv_kernel(
    const unsigned short* __restrict__ xp, const unsigned short* __restrict__ wq,
    float* __restrict__ out) {
  __shared__ unsigned short patch[23040];  // 180 sp x 128 ch (46.1 KB)

  const int tid = threadIdx.x;
  const int blk = blockIdx.x;
  const int b = blk & 31;        // image
  const int tile = blk >> 5;     // 0..27 = hi*4 + wi
  const int hi = tile >> 2;      // 0..6
  const int wi = tile & 3;
  const int h0 = hi * 8;
  const int w0 = (wi == 3) ? 40 : wi * 16;

  const int lane = tid & 63;
  const int wave = tid >> 6;
  const int mh = wave >> 1;
  const int nh = wave & 1;
  const int l15 = lane & 15;
  const int quad = lane >> 4;

  // per-lane B base: covers quad + nh + l15; per-step stride 4096 shorts,
  // per-nf stride 128 shorts.
  const unsigned short* wlane =
      wq + ((size_t)quad * 128 + nh * 64 + l15) * 8;

  // ---- prologue: B prefetch for steps 0,1; latency hides under staging ----
  bf16x8 b0[4], b1[4], b2[4], b3[4];
  #pragma unroll
  for (int nf = 0; nf < 4; ++nf)
    b0[nf] = *(const bf16x8*)(wlane + nf * 128);
  #pragma unroll
  for (int nf = 0; nf < 4; ++nf)
    b1[nf] = *(const bf16x8*)(wlane + (size_t)4096 + nf * 128);

  // ---- stage patch: 180 sp (10 rows x 18 px) x 16 chunks, swizzled ----
  const size_t rowstride = 58 * 128;
  for (int i = tid; i < 2880; i += 256) {
    int sp = i >> 4;
    int c16 = i & 15;
    int ph = sp / 18;           // 0..9
    int pw = sp - ph * 18;      // 0..17
    const unsigned short* gp = xp + ((size_t)b * 58 + (h0 + ph)) * rowstride +
                               (size_t)(w0 + pw) * 128 + c16 * 8;
    uint4 v = *(const uint4*)gp;
    *(uint4*)&patch[sp * 128 + ((c16 ^ (sp & 7)) << 3)] = v;
  }
  __syncthreads();  // patch ready -- the ONLY barrier in this kernel

  f32x4 acc[4][4];
  #pragma unroll
  for (int mf = 0; mf < 4; ++mf)
    #pragma unroll
    for (int nf = 0; nf < 4; ++nf) acc[mf][nf] = (f32x4)0.f;

  // step s = t*4 + kb, t = tap (kh,kw), kb = 32-ch K-slice.
  auto pf_af = [&](int s, bf16x8 (&af)[4]) {
    const int sc = (s < 36) ? s : 35;  // clamped dup on final iters, unused
    const int t = sc >> 2;
    const int kb = sc & 3;
    const int kh = (t * 11) >> 5;  // t/3 for t in 0..8
    const int kw = t - 3 * kh;
    #pragma unroll
    for (int mf = 0; mf < 4; ++mf) {
      const int sp = (mh * 4 + mf + kh) * 18 + l15 + kw;
      af[mf] = *(const bf16x8*)&patch[sp * 128 +
                                      (((kb * 4 + quad) ^ (sp & 7)) << 3)];
    }
  };
  auto pf_b = [&](int s, bf16x8 (&br)[4]) {
    const int sc = (s < 36) ? s : 35;  // clamped dup on final iters, unused
    #pragma unroll
    for (int nf = 0; nf < 4; ++nf)
      br[nf] = *(const bf16x8*)(wlane + (size_t)sc * 4096 + nf * 128);
  };
  auto compute = [&](bf16x8 (&af)[4], bf16x8 (&br)[4]) {
    #pragma unroll
    for (int mf = 0; mf < 4; ++mf)
      #pragma unroll
      for (int nf = 0; nf < 4; ++nf)
        acc[mf][nf] = __builtin_amdgcn_mfma_f32_16x16x32_bf16(
            af[mf], br[nf], acc[mf][nf], 0, 0, 0);
  };

  bf16x8 afA[4], afB[4];
  pf_af(0, afA);  // first-use stall once, then pipelined

  #pragma unroll 1
  for (int d = 0; d < 9; ++d) {
    const int s = d * 4;
    pf_af(s + 1, afB); pf_b(s + 2, b2); compute(afA, b0);
    pf_af(s + 2, afA); pf_b(s + 3, b3); compute(afB, b1);
    pf_af(s + 3, afB); pf_b(s + 4, b0); compute(afA, b2);
    pf_af(s + 4, afA); pf_b(s + 5, b1); compute(afB, b3);
  }

  // ---- epilogue: lane's f32x4 = w0+quad*4..+3 at h = h0+mh*4+mf, cout o.
  // Full 64-B sectors per (o,h); normal stores (R6 lesson: NT stores
  // amplify HBM writes). ----
  #pragma unroll
  for (int mf = 0; mf < 4; ++mf) {
    int h = h0 + mh * 4 + mf;
    #pragma unroll
    for (int nf = 0; nf < 4; ++nf) {
      int o = nh * 64 + nf * 16 + l15;
      float* p = out + (((size_t)b * 128 + o) * 56 + h) * 56 + w0 + quad * 4;
      *(f32x4*)p = acc[mf][nf];
    }
  }
}

extern "C" void kernel_launch(void* const* d_in, const int* in_sizes, int n_in,
                              void* d_out, int out_size, void* d_ws, size_t ws_size,
                              hipStream_t stream) {
  const float* x = (const float*)d_in[0];       // [32,128,56,56]
  const float* w = (const float*)d_in[1];       // [5,128,128,3,3]
  const float* scales = (const float*)d_in[2];  // [5]
  float* out = (float*)d_out;                   // [32,128,56,56]

  float* csum_part = (float*)d_ws;                                    // 320 floats
  unsigned short* wq = (unsigned short*)((char*)d_ws + 4096);         // 36*4096 bf16
  unsigned short* xpad = (unsigned short*)((char*)d_ws + 512 * 1024); // 32*58*58*128 bf16

  prep_fused<<<1856 + 320, 256, 0, stream>>>(x, w, xpad, csum_part);
  binweight_kernel<<<576, 256, 0, stream>>>(w, csum_part, scales, wq);
  conv_kernel<<<28 * 32, 256, 0, stream>>>(xpad, wq, out);
}